// Round 14
// baseline (133.233 us; speedup 1.0000x reference)
//
#include <hip/hip_runtime.h>
#include <hip/hip_fp16.h>

#define NODE_DIM 128
#define EDGE_DIM 128
#define N_RADIAL 16
#define MAXZ     100
#define BLOCK    512
#define NWAVE    (BLOCK / 64)
#define MC       16            // edges per wave-private chunk (regs, not LDS)

typedef _Float16 h2  __attribute__((ext_vector_type(2)));
typedef float    fx2 __attribute__((ext_vector_type(2)));
typedef float    fx4 __attribute__((ext_vector_type(4)));

__device__ __forceinline__ float fdot2f(h2 a, h2 b, float c) {
#if __has_builtin(__builtin_amdgcn_fdot2)
    return __builtin_amdgcn_fdot2(a, b, c, false);
#else
    return c + (float)a.x * (float)b.x + (float)a.y * (float)b.y;
#endif
}

__device__ __forceinline__ int pk16i(float x, float y) {
#if __has_builtin(__builtin_amdgcn_cvt_pkrtz)
    return __builtin_bit_cast(int, __builtin_amdgcn_cvt_pkrtz(x, y));
#else
    h2 v; v.x = (_Float16)x; v.y = (_Float16)y;
    return __builtin_bit_cast(int, v);
#endif
}

// ---------------------------------------------------------------------------
// Precompute (tables only, 108 blocks).
//  blocks [0, max_z)       : fp16 node tables t1/t2
//  blocks [max_z, max_z+8) : pair-packed fp16 rbf matrix w3h
// ---------------------------------------------------------------------------
__global__ void precompute_tables(const float* __restrict__ embed_table,
                                  const float* __restrict__ edge_w,
                                  const float* __restrict__ edge_b,
                                  const float* __restrict__ rbf_w,
                                  __half* __restrict__ tH,
                                  h2* __restrict__ w3h,
                                  int max_z) {
    const int d = threadIdx.x;
    if ((int)blockIdx.x < max_z) {
        const int r = blockIdx.x;
        float s1 = edge_b[d];
        float s2 = 0.0f;
        const float* er = embed_table + (long)r * NODE_DIM;
#pragma unroll 8
        for (int k = 0; k < NODE_DIM; ++k) {
            const float e = er[k];
            s1 += e * edge_w[(long)k * EDGE_DIM + d];
            s2 += e * edge_w[(long)(NODE_DIM + k) * EDGE_DIM + d];
        }
        tH[(long)r * EDGE_DIM + d]          = __float2half(s1);
        tH[(long)(MAXZ + r) * EDGE_DIM + d] = __float2half(s2);
    } else {
        const int kk = blockIdx.x - max_z;    // 0..7
        const float* ra = rbf_w + (long)(2 * kk)     * EDGE_DIM;
        const float* rb = rbf_w + (long)(2 * kk + 1) * EDGE_DIM;
        float sa = 0.0f, sb = 0.0f;
#pragma unroll 8
        for (int k = 0; k < EDGE_DIM; ++k) {
            const float wkd = edge_w[(long)(2 * NODE_DIM + k) * EDGE_DIM + d];
            sa += ra[k] * wkd;
            sb += rb[k] * wkd;
        }
        h2 v; v.x = (_Float16)sa; v.y = (_Float16)sb;
        w3h[kk * EDGE_DIM + d] = v;
    }
}

// ---------------------------------------------------------------------------
// Main kernel (R13 structure).  Two changes under test:
//  (a) out stores are NORMAL (write-back) instead of nontemporal — isolating
//      the store-polarity half of R11's combined flip.  Fill kernels prove
//      normal stores reach 6.9 TB/s; nt-stores may throttle at ~4.2.
//  (b) the idx->z 2-hop gather is predicated to lanes 0-15 (only their
//      results are consumed via readlane; readlane ignores exec) — removes
//      4x redundant scattered L2 requests.
// Everything else identical: table-only LDS (3 blocks/CU), chunk-ahead
// register staging, readlane distribution, cached rbf loads, fdot2.
// ---------------------------------------------------------------------------
__global__ void __launch_bounds__(BLOCK, 6) edge_main(
        const float* __restrict__ rbf,
        const int*   __restrict__ z,
        const int*   __restrict__ idx_i,
        const int*   __restrict__ idx_j,
        const h2*    __restrict__ tabg,    // 2*MAXZ rows of 64 h2
        const h2*    __restrict__ w3h,     // 8*128 h2
        float* __restrict__ out,
        int n_edges) {
    __shared__ h2 sTab[2 * MAXZ * 64];                 // 51200 B, only LDS

    const int tid  = threadIdx.x;
    const int lane = tid & 63;

    // this lane's 2 output cols of w3c (pair-packed over kk) -> 16 VGPRs
    h2 w[8][2];
#pragma unroll
    for (int kk = 0; kk < 8; ++kk) {
        const uint2 u = *reinterpret_cast<const uint2*>(
            &w3h[kk * EDGE_DIM + 2 * lane]);
        w[kk][0] = __builtin_bit_cast(h2, u.x);
        w[kk][1] = __builtin_bit_cast(h2, u.y);
    }

    // cooperative copy of the table into LDS (3200 uint4)
    {
        const uint4* src = reinterpret_cast<const uint4*>(tabg);
        uint4*       dst = reinterpret_cast<uint4*>(sTab);
        for (int i = tid; i < (2 * MAXZ * EDGE_DIM) / 8; i += BLOCK)
            dst[i] = src[i];
    }
    __syncthreads();   // only barrier

    // contiguous chunk range for this wave
    const int W   = gridDim.x * NWAVE;
    const int gw  = blockIdx.x * NWAVE + (tid >> 6);
    const int nmc = (n_edges + MC - 1) / MC;
    const int mlo = (int)(((long)gw * nmc) / W);
    const int mhi = (int)(((long)(gw + 1) * nmc) / W);
    if (mlo >= mhi) return;

    const fx4* rbf4 = reinterpret_cast<const fx4*>(rbf);
    const int  emax = n_edges - 1;
    const int  eoff = lane >> 2;        // which of the 16 edges this lane stages
    const int  eqtr = lane & 3;         // which quarter-row this lane stages
    const bool zlan = lane < MC;        // only these lanes gather z

#define GETZP(E) ((z[idx_j[(E)]] & 0xffff) | (z[idx_i[(E)]] << 16))
#define CLAMP(E) ((E) < emax ? (E) : emax)

    // ---- prologue: stage chunk mlo into registers ----
    int rs0, rs1, zs = 0;
    {
        const int e = CLAMP(mlo * MC + eoff);
        const fx4 v = rbf4[(long)e * 4 + eqtr];        // cached load (L3-hot)
        rs0 = pk16i(v.x, v.y);
        rs1 = pk16i(v.z, v.w);
        if (zlan) zs = GETZP(CLAMP(mlo * MC + lane));
    }

    for (int m = mlo; m < mhi; ++m) {
        const bool hasn = (m + 1) < mhi;

        // ---- issue next-chunk loads first (held in regs until rotation) ----
        fx4 nv = (fx4)0.0f;
        int nz = 0;
        if (hasn) {
            const int e = CLAMP((m + 1) * MC + eoff);
            nv = rbf4[(long)e * 4 + eqtr];             // cached load (L3-hot)
            if (zlan) nz = GETZP(CLAMP((m + 1) * MC + lane));
        }

        // ---- compute the 16 edges of chunk m, one edge per wave-step ----
        const int base = m * MC;
#pragma unroll
        for (int s = 0; s < MC; ++s) {
            const int eg = base + s;

            // z pair broadcast (uniform, static lane s; lane s<16 wrote zs)
            const int zp = __builtin_amdgcn_readlane(zs, s);
            const int zj = zp & 0xffff;
            const int zi = zp >> 16;

            // table h2 for this lane's 2 cols (2 x ds_read_b32, 2-way alias)
            const h2 tj = sTab[zj * 64 + lane];
            const h2 ti = sTab[(MAXZ + zi) * 64 + lane];

            // rbf row: 8 packed-h2 dwords broadcast from static lanes
            h2 rb[8];
#pragma unroll
            for (int t = 0; t < 8; ++t) {
                const int src = (s << 2) | (t >> 1);
                const int d   = __builtin_amdgcn_readlane((t & 1) ? rs1 : rs0,
                                                          src);
                rb[t] = __builtin_bit_cast(h2, d);
            }

            // acc init = t1[zj] + t2[zi] (packed fp16 add), widen to fp32
            const h2 t = tj + ti;
            float a0 = (float)t.x;
            float a1 = (float)t.y;

#pragma unroll
            for (int kk = 0; kk < 8; ++kk) {
                a0 = fdot2f(rb[kk], w[kk][0], a0);
                a1 = fdot2f(rb[kk], w[kk][1], a1);
            }

            // swish via fast rcp
            fx2 o;
            o.x = a0 * __builtin_amdgcn_rcpf(1.0f + __expf(-a0));
            o.y = a1 * __builtin_amdgcn_rcpf(1.0f + __expf(-a1));

            if (eg <= emax)
                *reinterpret_cast<fx2*>(
                    &out[(size_t)eg * EDGE_DIM + 2 * lane]) = o;   // NORMAL store
        }

        // ---- rotate staging ----
        if (hasn) {
            rs0 = pk16i(nv.x, nv.y);
            rs1 = pk16i(nv.z, nv.w);
            zs  = nz;
        }
    }
#undef GETZP
#undef CLAMP
}

extern "C" void kernel_launch(void* const* d_in, const int* in_sizes, int n_in,
                              void* d_out, int out_size, void* d_ws, size_t ws_size,
                              hipStream_t stream) {
    const int*   zp          = (const int*)  d_in[0];
    const float* rbf         = (const float*)d_in[1];
    const int*   idx_i       = (const int*)  d_in[2];
    const int*   idx_j       = (const int*)  d_in[3];
    const float* embed_table = (const float*)d_in[4];
    const float* rbf_w       = (const float*)d_in[5];
    const float* edge_w      = (const float*)d_in[6];
    const float* edge_b      = (const float*)d_in[7];

    int max_z = in_sizes[4] / NODE_DIM;           // 100
    if (max_z > MAXZ) max_z = MAXZ;
    const int n_edges = in_sizes[2];              // 800000

    const size_t tab_bytes = (size_t)2 * MAXZ * EDGE_DIM * sizeof(__half); // 51200
    __half* tH  = (__half*)d_ws;
    h2*     w3h = (h2*)((char*)d_ws + tab_bytes);
    float*  out = (float*)d_out;

    precompute_tables<<<max_z + 8, EDGE_DIM, 0, stream>>>(
        embed_table, edge_w, edge_b, rbf_w, tH, w3h, max_z);

    const int grid = 768;   // 3 blocks/CU (LDS 51.2 KB each)
    edge_main<<<grid, BLOCK, 0, stream>>>(rbf, zp, idx_i, idx_j,
                                          (const h2*)tH, w3h, out, n_edges);
}

// Round 15
// 104.420 us; speedup vs baseline: 1.2759x; 1.2759x over previous
//
#include <hip/hip_runtime.h>
#include <hip/hip_fp16.h>

#define NODE_DIM 128
#define EDGE_DIM 128
#define N_RADIAL 16
#define MAXZ     100
#define BLOCK    512
#define NWAVE    (BLOCK / 64)
#define MC       16            // edges per wave-private chunk (regs, not LDS)

typedef _Float16 h2  __attribute__((ext_vector_type(2)));
typedef float    fx2 __attribute__((ext_vector_type(2)));
typedef float    fx4 __attribute__((ext_vector_type(4)));

__device__ __forceinline__ float fdot2f(h2 a, h2 b, float c) {
#if __has_builtin(__builtin_amdgcn_fdot2)
    return __builtin_amdgcn_fdot2(a, b, c, false);
#else
    return c + (float)a.x * (float)b.x + (float)a.y * (float)b.y;
#endif
}

__device__ __forceinline__ int pk16i(float x, float y) {
#if __has_builtin(__builtin_amdgcn_cvt_pkrtz)
    return __builtin_bit_cast(int, __builtin_amdgcn_cvt_pkrtz(x, y));
#else
    h2 v; v.x = (_Float16)x; v.y = (_Float16)y;
    return __builtin_bit_cast(int, v);
#endif
}

// ---------------------------------------------------------------------------
// Precompute (tables only, 108 blocks).
//  blocks [0, max_z)       : fp16 node tables t1/t2
//  blocks [max_z, max_z+8) : pair-packed fp16 rbf matrix w3h
// ---------------------------------------------------------------------------
__global__ void precompute_tables(const float* __restrict__ embed_table,
                                  const float* __restrict__ edge_w,
                                  const float* __restrict__ edge_b,
                                  const float* __restrict__ rbf_w,
                                  __half* __restrict__ tH,
                                  h2* __restrict__ w3h,
                                  int max_z) {
    const int d = threadIdx.x;
    if ((int)blockIdx.x < max_z) {
        const int r = blockIdx.x;
        float s1 = edge_b[d];
        float s2 = 0.0f;
        const float* er = embed_table + (long)r * NODE_DIM;
#pragma unroll 8
        for (int k = 0; k < NODE_DIM; ++k) {
            const float e = er[k];
            s1 += e * edge_w[(long)k * EDGE_DIM + d];
            s2 += e * edge_w[(long)(NODE_DIM + k) * EDGE_DIM + d];
        }
        tH[(long)r * EDGE_DIM + d]          = __float2half(s1);
        tH[(long)(MAXZ + r) * EDGE_DIM + d] = __float2half(s2);
    } else {
        const int kk = blockIdx.x - max_z;    // 0..7
        const float* ra = rbf_w + (long)(2 * kk)     * EDGE_DIM;
        const float* rb = rbf_w + (long)(2 * kk + 1) * EDGE_DIM;
        float sa = 0.0f, sb = 0.0f;
#pragma unroll 8
        for (int k = 0; k < EDGE_DIM; ++k) {
            const float wkd = edge_w[(long)(2 * NODE_DIM + k) * EDGE_DIM + d];
            sa += ra[k] * wkd;
            sb += rb[k] * wkd;
        }
        h2 v; v.x = (_Float16)sa; v.y = (_Float16)sb;
        w3h[kk * EDGE_DIM + d] = v;
    }
}

// ---------------------------------------------------------------------------
// Main kernel: LDS = fp16 table ONLY (51.2 KB -> 3 blocks/CU, 24 waves/CU).
// ONE edge per wave-step; lane owns 2 output columns.  The idx->z 2-hop
// gather is FUSED into the chunk-ahead register staging (no prepass): it is
// issued a full chunk (~1600 issue-cycles) ahead, so the ~600-1200 cyc chain
// through L2 (z table = 200 KB, L2-resident) hides under compute + TLP.
// Cross-lane distribution via v_readlane (static lane, zero LDS-pipe cost).
// rbf loads cached (L3-resident across graph replays); out stores
// nontemporal (keep L3 clean for rbf).  No in-loop barriers.
// ---------------------------------------------------------------------------
__global__ void __launch_bounds__(BLOCK, 6) edge_main(
        const float* __restrict__ rbf,
        const int*   __restrict__ z,
        const int*   __restrict__ idx_i,
        const int*   __restrict__ idx_j,
        const h2*    __restrict__ tabg,    // 2*MAXZ rows of 64 h2
        const h2*    __restrict__ w3h,     // 8*128 h2
        float* __restrict__ out,
        int n_edges) {
    __shared__ h2 sTab[2 * MAXZ * 64];                 // 51200 B, only LDS

    const int tid  = threadIdx.x;
    const int lane = tid & 63;

    // this lane's 2 output cols of w3c (pair-packed over kk) -> 16 VGPRs
    h2 w[8][2];
#pragma unroll
    for (int kk = 0; kk < 8; ++kk) {
        const uint2 u = *reinterpret_cast<const uint2*>(
            &w3h[kk * EDGE_DIM + 2 * lane]);
        w[kk][0] = __builtin_bit_cast(h2, u.x);
        w[kk][1] = __builtin_bit_cast(h2, u.y);
    }

    // cooperative copy of the table into LDS (3200 uint4)
    {
        const uint4* src = reinterpret_cast<const uint4*>(tabg);
        uint4*       dst = reinterpret_cast<uint4*>(sTab);
        for (int i = tid; i < (2 * MAXZ * EDGE_DIM) / 8; i += BLOCK)
            dst[i] = src[i];
    }
    __syncthreads();   // only barrier

    // contiguous chunk range for this wave
    const int W   = gridDim.x * NWAVE;
    const int gw  = blockIdx.x * NWAVE + (tid >> 6);
    const int nmc = (n_edges + MC - 1) / MC;
    const int mlo = (int)(((long)gw * nmc) / W);
    const int mhi = (int)(((long)(gw + 1) * nmc) / W);
    if (mlo >= mhi) return;

    const fx4* rbf4 = reinterpret_cast<const fx4*>(rbf);
    const int  emax = n_edges - 1;
    const int  eoff = lane >> 2;        // which of the 16 edges this lane stages
    const int  eqtr = lane & 3;         // which quarter-row this lane stages
    const int  zoff = lane & 15;        // which edge's z this lane stages

#define GETZP(E) ((z[idx_j[(E)]] & 0xffff) | (z[idx_i[(E)]] << 16))
#define CLAMP(E) ((E) < emax ? (E) : emax)

    // ---- prologue: stage chunk mlo into registers ----
    int rs0, rs1, zs;
    {
        const int e = CLAMP(mlo * MC + eoff);
        const fx4 v = rbf4[(long)e * 4 + eqtr];        // cached load (L3-hot)
        rs0 = pk16i(v.x, v.y);
        rs1 = pk16i(v.z, v.w);
        zs  = GETZP(CLAMP(mlo * MC + zoff));
    }

    for (int m = mlo; m < mhi; ++m) {
        const bool hasn = (m + 1) < mhi;

        // ---- issue next-chunk loads first (held in regs until rotation) ----
        fx4 nv = (fx4)0.0f;
        int nz = 0;
        if (hasn) {
            const int e = CLAMP((m + 1) * MC + eoff);
            nv = rbf4[(long)e * 4 + eqtr];             // cached load (L3-hot)
            nz = GETZP(CLAMP((m + 1) * MC + zoff));
        }

        // ---- compute the 16 edges of chunk m, one edge per wave-step ----
        const int base = m * MC;
#pragma unroll
        for (int s = 0; s < MC; ++s) {
            const int eg = base + s;

            // z pair broadcast (uniform, static lane s)
            const int zp = __builtin_amdgcn_readlane(zs, s);
            const int zj = zp & 0xffff;
            const int zi = zp >> 16;

            // table h2 for this lane's 2 cols (2 x ds_read_b32, 2-way alias)
            const h2 tj = sTab[zj * 64 + lane];
            const h2 ti = sTab[(MAXZ + zi) * 64 + lane];

            // rbf row: 8 packed-h2 dwords broadcast from static lanes
            h2 rb[8];
#pragma unroll
            for (int t = 0; t < 8; ++t) {
                const int src = (s << 2) | (t >> 1);
                const int d   = __builtin_amdgcn_readlane((t & 1) ? rs1 : rs0,
                                                          src);
                rb[t] = __builtin_bit_cast(h2, d);
            }

            // acc init = t1[zj] + t2[zi] (packed fp16 add), widen to fp32
            const h2 t = tj + ti;
            float a0 = (float)t.x;
            float a1 = (float)t.y;

#pragma unroll
            for (int kk = 0; kk < 8; ++kk) {
                a0 = fdot2f(rb[kk], w[kk][0], a0);
                a1 = fdot2f(rb[kk], w[kk][1], a1);
            }

            // swish via fast rcp
            fx2 o;
            o.x = a0 * __builtin_amdgcn_rcpf(1.0f + __expf(-a0));
            o.y = a1 * __builtin_amdgcn_rcpf(1.0f + __expf(-a1));

            if (eg <= emax)
                __builtin_nontemporal_store(o, reinterpret_cast<fx2*>(
                    &out[(size_t)eg * EDGE_DIM + 2 * lane]));
        }

        // ---- rotate staging ----
        if (hasn) {
            rs0 = pk16i(nv.x, nv.y);
            rs1 = pk16i(nv.z, nv.w);
            zs  = nz;
        }
    }
#undef GETZP
#undef CLAMP
}

extern "C" void kernel_launch(void* const* d_in, const int* in_sizes, int n_in,
                              void* d_out, int out_size, void* d_ws, size_t ws_size,
                              hipStream_t stream) {
    const int*   zp          = (const int*)  d_in[0];
    const float* rbf         = (const float*)d_in[1];
    const int*   idx_i       = (const int*)  d_in[2];
    const int*   idx_j       = (const int*)  d_in[3];
    const float* embed_table = (const float*)d_in[4];
    const float* rbf_w       = (const float*)d_in[5];
    const float* edge_w      = (const float*)d_in[6];
    const float* edge_b      = (const float*)d_in[7];

    int max_z = in_sizes[4] / NODE_DIM;           // 100
    if (max_z > MAXZ) max_z = MAXZ;
    const int n_edges = in_sizes[2];              // 800000

    const size_t tab_bytes = (size_t)2 * MAXZ * EDGE_DIM * sizeof(__half); // 51200
    __half* tH  = (__half*)d_ws;
    h2*     w3h = (h2*)((char*)d_ws + tab_bytes);
    float*  out = (float*)d_out;

    precompute_tables<<<max_z + 8, EDGE_DIM, 0, stream>>>(
        embed_table, edge_w, edge_b, rbf_w, tH, w3h, max_z);

    const int grid = 768;   // 3 blocks/CU (LDS 51.2 KB each)
    edge_main<<<grid, BLOCK, 0, stream>>>(rbf, zp, idx_i, idx_j,
                                          (const h2*)tH, w3h, out, n_edges);
}